// Round 9
// baseline (236.971 us; speedup 1.0000x reference)
//
#include <hip/hip_runtime.h>
#include <hip/hip_bf16.h>

#define B_ 64
#define N_ 4096
#define F_ 512
#define D_ 256
#define BM 64
#define APAD 520                 // halves per LDS row (1040 B)
#define NCHUNK (N_ / BM)         // 64 chunks per batch
#define GT 16                    // tiles per block
#define NBLK (B_ * NCHUNK / GT)  // 256 blocks

typedef __attribute__((ext_vector_type(8))) short short8;
typedef __attribute__((ext_vector_type(4))) float f32x4;

__device__ __forceinline__ unsigned short f2bf(float f) {
  unsigned int u = __float_as_uint(f);
  u += 0x7FFFu + ((u >> 16) & 1u);   // RNE round to bf16
  return (unsigned short)(u >> 16);
}

__device__ __forceinline__ unsigned int pk2bf(float x, float y) {
  float2 f; f.x = x; f.y = y;
  __hip_bfloat162 h = __float22bfloat162_rn(f);   // v_cvt_pk_bf16_f32
  union { __hip_bfloat162 h2; unsigned int u; } cv; cv.h2 = h;
  return cv.u;                                    // x in low 16 bits
}

__device__ __forceinline__ float fast_tanh(float x) {
  float e = __expf(-2.0f * fabsf(x));
  float t = (1.0f - e) / (1.0f + e);
  return copysignf(t, x);
}

// raw barrier: no vmcnt drain (prefetch loads stay in flight)
#define SBAR                                                                   \
  do {                                                                         \
    __builtin_amdgcn_sched_barrier(0);                                         \
    __builtin_amdgcn_s_barrier();                                              \
    __builtin_amdgcn_sched_barrier(0);                                         \
  } while (0)

#define LGKM0                                                                  \
  do {                                                                         \
    asm volatile("s_waitcnt lgkmcnt(0)" ::: "memory");                         \
    __builtin_amdgcn_sched_barrier(0);                                         \
  } while (0)

// ---- prep: W_img f32 [256][512] -> bf16 in exact MFMA B-fragment order.
// frag g = q*16 + d16 (q = K-step-32 idx 0..15): idx = ((g)*64 + lane)*8 + e
__global__ void prep_w_kernel(const float* __restrict__ Wimg,
                              unsigned short* __restrict__ wfrag) {
  int d = blockIdx.x;        // 0..255
  int f = threadIdx.x;       // 0..511
  int q = f >> 5, lg = (f >> 3) & 3, e = f & 7;
  int lr = d & 15, d16 = d >> 4;
  int lane = lg * 16 + lr;
  int idx = ((q * 16 + d16) * 64 + lane) * 8 + e;
  wfrag[idx] = f2bf(Wimg[d * F_ + f]);
}

// ---- prep: proj_hidden[b][d]
__global__ void prep_ph_kernel(const float* __restrict__ hid,
                               const float* __restrict__ Whid,
                               float* __restrict__ ph) {
  int b = blockIdx.x, d = threadIdx.x;  // 64 x 256
  const float4* hv = (const float4*)(hid + b * F_);
  const float4* wv = (const float4*)(Whid + d * F_);
  float acc = 0.f;
#pragma unroll 4
  for (int i = 0; i < 128; i++) {
    float4 h = hv[i], w = wv[i];
    acc += h.x * w.x + h.y * w.y + h.z * w.z + h.w * w.w;
  }
  ph[b * D_ + d] = acc;
}

// ---- fused: B-in-registers multi-tile GEMM + tanh + score + ctx partial
__global__ __launch_bounds__(512, 2) void fused_kernel(
    const float* __restrict__ feat, const unsigned short* __restrict__ wfrag,
    const float* __restrict__ ph, const float* __restrict__ wscore,
    float* __restrict__ expw, float2* __restrict__ meta,
    float* __restrict__ part) {
  __shared__ unsigned short Afull[BM * APAD];   // 65 KiB bf16 feat tile
  __shared__ float red[BM][8];
  __shared__ float sbuf[BM];
  __shared__ float ewf[BM];

  int tid = threadIdx.x;
  int lane = tid & 63, wn = tid >> 6;      // 8 waves; wave wn owns d-cols [wn*32, wn*32+32)
  int lr = lane & 15, lg = lane >> 4;

  int blk = blockIdx.x;                    // 256
  int b = blk >> 2, j = blk & 3;           // 4 blocks per batch, 16 tiles each

  // ---- B operand: entire wave-quadrant in registers (32 short8 = 128 VGPR)
  short8 bq[16][2];
#pragma unroll
  for (int q = 0; q < 16; q++)
#pragma unroll
    for (int n = 0; n < 2; n++)
      bq[q][n] = *(const short8*)(wfrag +
          (size_t)((q * 16 + wn * 2 + n) * 64 + lane) * 8);

  float ph2[2], ws2[2];
#pragma unroll
  for (int n = 0; n < 2; n++) {
    int d = wn * 32 + n * 16 + lr;
    ph2[n] = ph[b * D_ + d];
    ws2[n] = wscore[d];
  }

  // A staging: 512 threads cover a 64x64 f32 slice; thread: row=tid>>3, 8 cols
  int row_s = tid >> 3, c0 = (tid & 7) * 8;
  const float* arow = feat + ((size_t)b * N_ + (size_t)j * GT * BM) * F_;

#define LOADS(buf, ptr, kt_)                                                   \
  do {                                                                         \
    buf##_0 = *(const float4*)((ptr) + (size_t)row_s * F_ + (kt_)*64 + c0);    \
    buf##_1 = *(const float4*)((ptr) + (size_t)row_s * F_ + (kt_)*64 + c0 + 4);\
  } while (0)

#define CVTW(buf, kt_)                                                         \
  do {                                                                         \
    uint4 wv; wv.x = pk2bf(buf##_0.x, buf##_0.y);                              \
    wv.y = pk2bf(buf##_0.z, buf##_0.w);                                        \
    wv.z = pk2bf(buf##_1.x, buf##_1.y);                                        \
    wv.w = pk2bf(buf##_1.z, buf##_1.w);                                        \
    *(uint4*)(Afull + row_s * APAD + (kt_)*64 + c0) = wv;                      \
  } while (0)

#define QQ(q_)                                                                 \
  do {                                                                         \
    short8 af0 = *(const short8*)(Afull + (0 * 16 + lr) * APAD + (q_)*32 + lg * 8); \
    short8 af1 = *(const short8*)(Afull + (1 * 16 + lr) * APAD + (q_)*32 + lg * 8); \
    short8 af2 = *(const short8*)(Afull + (2 * 16 + lr) * APAD + (q_)*32 + lg * 8); \
    short8 af3 = *(const short8*)(Afull + (3 * 16 + lr) * APAD + (q_)*32 + lg * 8); \
    acc[0][0] = __builtin_amdgcn_mfma_f32_16x16x32_bf16(af0, bq[q_][0], acc[0][0], 0, 0, 0); \
    acc[0][1] = __builtin_amdgcn_mfma_f32_16x16x32_bf16(af0, bq[q_][1], acc[0][1], 0, 0, 0); \
    acc[1][0] = __builtin_amdgcn_mfma_f32_16x16x32_bf16(af1, bq[q_][0], acc[1][0], 0, 0, 0); \
    acc[1][1] = __builtin_amdgcn_mfma_f32_16x16x32_bf16(af1, bq[q_][1], acc[1][1], 0, 0, 0); \
    acc[2][0] = __builtin_amdgcn_mfma_f32_16x16x32_bf16(af2, bq[q_][0], acc[2][0], 0, 0, 0); \
    acc[2][1] = __builtin_amdgcn_mfma_f32_16x16x32_bf16(af2, bq[q_][1], acc[2][1], 0, 0, 0); \
    acc[3][0] = __builtin_amdgcn_mfma_f32_16x16x32_bf16(af3, bq[q_][0], acc[3][0], 0, 0, 0); \
    acc[3][1] = __builtin_amdgcn_mfma_f32_16x16x32_bf16(af3, bq[q_][1], acc[3][1], 0, 0, 0); \
  } while (0)

  float4 rs0_0, rs0_1, rs1_0, rs1_1;
  // prologue: tile 0 slices 0,1
  LOADS(rs0, arow, 0);
  LOADS(rs1, arow, 1);

#pragma unroll 1
  for (int t = 0; t < GT; t++) {
    const float* nrow = (t < GT - 1) ? (arow + (size_t)BM * F_) : arow;
    f32x4 acc[4][2];
#pragma unroll
    for (int m = 0; m < 4; m++)
#pragma unroll
      for (int n = 0; n < 2; n++) acc[m][n] = (f32x4)0.f;

    // invariant at entry: rs0 = this tile slice 0, rs1 = slice 1 (in flight/held)
    CVTW(rs0, 0); LGKM0; SBAR;
    LOADS(rs0, arow, 2); QQ(0);  QQ(1);  CVTW(rs1, 1); LGKM0; SBAR;
    LOADS(rs1, arow, 3); QQ(2);  QQ(3);  CVTW(rs0, 2); LGKM0; SBAR;
    LOADS(rs0, arow, 4); QQ(4);  QQ(5);  CVTW(rs1, 3); LGKM0; SBAR;
    LOADS(rs1, arow, 5); QQ(6);  QQ(7);  CVTW(rs0, 4); LGKM0; SBAR;
    LOADS(rs0, arow, 6); QQ(8);  QQ(9);  CVTW(rs1, 5); LGKM0; SBAR;
    LOADS(rs1, arow, 7); QQ(10); QQ(11); CVTW(rs0, 6); LGKM0; SBAR;
    LOADS(rs0, nrow, 0); QQ(12); QQ(13); CVTW(rs1, 7); LGKM0; SBAR;
    LOADS(rs1, nrow, 1); QQ(14); QQ(15);
    // exit: rs0/rs1 hold next tile slices 0/1

    // ---- scores: s[row] = sum_d tanh(proj + ph) * wscore (wave partials)
#pragma unroll
    for (int m = 0; m < 4; m++) {
#pragma unroll
      for (int jj = 0; jj < 4; jj++) {
        float p = fast_tanh(acc[m][0][jj] + ph2[0]) * ws2[0] +
                  fast_tanh(acc[m][1][jj] + ph2[1]) * ws2[1];
        p += __shfl_xor(p, 1);
        p += __shfl_xor(p, 2);
        p += __shfl_xor(p, 4);
        p += __shfl_xor(p, 8);
        if (lr == 0) red[m * 16 + lg * 4 + jj][wn] = p;
      }
    }
    __syncthreads();
    if (tid < BM) {
      float s = 0.f;
#pragma unroll
      for (int w = 0; w < 8; w++) s += red[tid][w];
      sbuf[tid] = s;
    }
    __syncthreads();

    int tile = j * GT + t;
    int n0 = tile * BM;
    // block-local softmax partials
    float mb = -1e30f;
#pragma unroll
    for (int r = 0; r < BM; r++) mb = fmaxf(mb, sbuf[r]);
    if (tid < BM) {
      float e = __expf(sbuf[tid] - mb);
      ewf[tid] = e;
      expw[b * N_ + n0 + tid] = e;
      float l = e;
#pragma unroll
      for (int o = 1; o < 64; o <<= 1) l += __shfl_xor(l, o);
      if (tid == 0) meta[b * NCHUNK + tile] = make_float2(mb, l);
    }
    __syncthreads();

    // ---- context partial from LDS bf16 tile: 512 threads x 1 col
    {
      float a = 0.f;
#pragma unroll 8
      for (int r = 0; r < BM; r++) {
        unsigned short v = Afull[r * APAD + tid];
        a += ewf[r] * __uint_as_float((unsigned int)v << 16);
      }
      part[(size_t)(b * NCHUNK + tile) * F_ + tid] = a;
    }
    __syncthreads();   // tile LDS free for next iteration's CVTW

    arow = nrow;
  }
}

// ---- finalize per batch: global softmax merge + context combine + weights
__global__ void finalize_kernel(const float* __restrict__ part,
                                const float2* __restrict__ meta,
                                const float* __restrict__ expw,
                                float* __restrict__ ctx,
                                float* __restrict__ wout) {
  __shared__ float sm[NCHUNK], sl[NCHUNK], se[NCHUNK];
  int b = blockIdx.x, t = threadIdx.x;   // 512 threads
  if (t < NCHUNK) {
    float2 ml = meta[b * NCHUNK + t];
    sm[t] = ml.x;
    sl[t] = ml.y;
  }
  __syncthreads();
  float M = -1e30f;
#pragma unroll 8
  for (int i = 0; i < NCHUNK; i++) M = fmaxf(M, sm[i]);
  float Z = 0.f;
#pragma unroll 8
  for (int i = 0; i < NCHUNK; i++) Z += sl[i] * __expf(sm[i] - M);
  if (t < NCHUNK) se[t] = __expf(sm[t] - M);
  __syncthreads();
  float invZ = 1.0f / Z;
  float acc = 0.f;
#pragma unroll 8
  for (int i = 0; i < NCHUNK; i++) acc += part[(size_t)(b * NCHUNK + i) * F_ + t] * se[i];
  ctx[b * F_ + t] = acc * invZ;
#pragma unroll
  for (int k = 0; k < 8; k++) {
    int n = k * 512 + t;
    wout[b * N_ + n] = expw[b * N_ + n] * se[n >> 6] * invZ;
  }
}

extern "C" void kernel_launch(void* const* d_in, const int* in_sizes, int n_in,
                              void* d_out, int out_size, void* d_ws, size_t ws_size,
                              hipStream_t stream) {
  const float* feat   = (const float*)d_in[0];   // [64,4096,512]
  const float* hid    = (const float*)d_in[1];   // [64,512]
  const float* Wimg   = (const float*)d_in[2];   // [256,512]
  const float* Whid   = (const float*)d_in[3];   // [256,512]
  const float* Wscore = (const float*)d_in[4];   // [1,256]

  float* ctx  = (float*)d_out;            // [64,512]
  float* wout = (float*)d_out + B_ * F_;  // [64,4096]

  // workspace layout
  unsigned short* wfrag = (unsigned short*)d_ws;                 // 256 KiB
  float*  ph    = (float*)((char*)d_ws + 262144);                // 64 KiB
  float*  expw  = (float*)((char*)d_ws + 327680);                // 1 MiB
  float2* meta  = (float2*)((char*)d_ws + 1376256);              // 32 KiB
  float*  part  = (float*)((char*)d_ws + 1409024);               // 8 MiB

  prep_w_kernel<<<D_, F_, 0, stream>>>(Wimg, wfrag);
  prep_ph_kernel<<<B_, D_, 0, stream>>>(hid, Whid, ph);
  fused_kernel<<<NBLK, 512, 0, stream>>>(feat, wfrag, ph, Wscore, expw, meta, part);
  finalize_kernel<<<B_, 512, 0, stream>>>(part, meta, expw, ctx, wout);
}